// Round 10
// baseline (1307.669 us; speedup 1.0000x reference)
//
#include <hip/hip_runtime.h>
#include <hip/hip_bf16.h>

// Elman RNN, round 14: r13 + conflict-free b128 h-writes via permlane16_swap.
// r13 post-mortem: total 1280 (best); scan core 1109 us dominates. Step = 1300
// cyc; DS pipe ~1024 (768 read + 64 write + 192 CONFLICT from the 16 b64
// 512B wave-writes: lanes i,i+16,i+32,i+48 share a bank pair = 4-way).
// Fix: v_permlane16_swap_b32 (gfx950) exchanges the two m-tiles' packed uint2
// across lane pairs (l, l+16) so each lane holds two ADJACENT woff entries of
// one slot -> ONE ds_write_b128 per wave covering a contiguous 1KB bijectively
// (canonical conflict-free). Reads unchanged. +2 permlane/wave-step.
// Also: gate cadence 64 -> 128 steps (16 gates). Everything else = r13.

#define BATCH 128
#define SEQ   2048
#define NIN   128
#define NH    256
#define NOUT  128

#define BTILE 16
#define NBLK  (BATCH / BTILE)      // 8
#define TCHUNK 8
#define NCHUNK (SEQ / TCHUNK)      // 256
#define GATE   128                 // consumer gate window (steps)
#define LOG2E 1.4426950408889634f

typedef __attribute__((ext_vector_type(8))) short short8;
typedef __attribute__((ext_vector_type(4))) float f32x4;
typedef unsigned int upair __attribute__((ext_vector_type(2)));

#if __has_builtin(__builtin_amdgcn_permlane16_swap)
#define USE_PL16 1
#else
#define USE_PL16 0
#endif

__device__ __forceinline__ ushort f2bf(float f) {
    union { float f; uint u; } v; v.f = f;
    uint r = v.u + 0x7fffu + ((v.u >> 16) & 1u);   // RNE
    return (ushort)(r >> 16);
}

// packed f32->bf16 RNE via builtin (m240: do not hand-write the asm)
__device__ __forceinline__ uint pk_bf16(float a, float b) {
    float2 p; p.x = a; p.y = b;
    __hip_bfloat162 h = __float22bfloat162_rn(p);
    union { __hip_bfloat162 h; uint u; } v; v.h = h; return v.u;
}

__device__ __forceinline__ short8 load_wfrag_s(const float* __restrict__ W, int ld,
                                               int row, int col, float scale) {
    const float4* p = (const float4*)(W + (size_t)row * ld + col);
    float4 a = p[0], b = p[1];
    union { short8 v; ushort u[8]; } r;
    r.u[0] = f2bf(a.x * scale); r.u[1] = f2bf(a.y * scale);
    r.u[2] = f2bf(a.z * scale); r.u[3] = f2bf(a.w * scale);
    r.u[4] = f2bf(b.x * scale); r.u[5] = f2bf(b.y * scale);
    r.u[6] = f2bf(b.z * scale); r.u[7] = f2bf(b.w * scale);
    return r.v;
}

__device__ __forceinline__ float bfhi2f(uint u) {
    union { uint u; float f; } v; v.u = u & 0xffff0000u; return v.f;
}
__device__ __forceinline__ float bflo2f(uint u) {
    union { uint u; float f; } v; v.u = u << 16; return v.f;
}

// =================== single-launch producer/consumer kernel ===================
__global__ __launch_bounds__(512, 2)
void elman_fused(const float* __restrict__ x,
                 const float* __restrict__ W_in,
                 const float* __restrict__ b_in,
                 const float* __restrict__ W_rec,
                 const float* __restrict__ W_out,
                 const float* __restrict__ b_out,
                 float* __restrict__ out,
                 uint2* __restrict__ xin,
                 uint*  __restrict__ flags) {
    const int tid  = threadIdx.x;
    const int lane = tid & 63;
    const int wid  = tid >> 6;          // 0..7
    const int n15  = lane & 15;
    const int q    = lane >> 4;

    __shared__ __align__(16) uint2 hlds[2][16 * 64];   // 16 KB static (consumer)

    if (blockIdx.x >= NBLK) {
        // ------------------------- producer -------------------------
        const int pid  = blockIdx.x - NBLK;
        const int c    = pid >> 3;
        const int b    = pid & 7;
        const int bblk = b * BTILE;
        const int t0   = c * TCHUNK;

        short8 win[2][4];
        float  bias[2][4];
        #pragma unroll
        for (int mt = 0; mt < 2; ++mt) {
            const int row = (wid * 2 + mt) * 16 + n15;
            #pragma unroll
            for (int kt = 0; kt < 4; ++kt)
                win[mt][kt] = load_wfrag_s(W_in, NIN, row, kt * 32 + q * 8, LOG2E);
            #pragma unroll
            for (int r = 0; r < 4; ++r)
                bias[mt][r] = LOG2E * b_in[(wid * 2 + mt) * 16 + q * 4 + r];
        }

        const float* xrow = x + ((size_t)(bblk + n15) * SEQ + t0) * NIN + q * 8;

        #pragma unroll 1
        for (int tt = 0; tt < TCHUNK; ++tt) {
            const float* xp = xrow + (size_t)tt * NIN;
            short8 bx[4];
            #pragma unroll
            for (int kt = 0; kt < 4; ++kt) {
                const float4* p = (const float4*)(xp + kt * 32);
                float4 a = p[0], bb = p[1];
                union { short8 v; uint u[4]; } r;
                r.u[0] = pk_bf16(a.x, a.y);
                r.u[1] = pk_bf16(a.z, a.w);
                r.u[2] = pk_bf16(bb.x, bb.y);
                r.u[3] = pk_bf16(bb.z, bb.w);
                bx[kt] = r.v;
            }
            f32x4 acc[2];
            #pragma unroll
            for (int mt = 0; mt < 2; ++mt) {
                acc[mt][0] = bias[mt][0]; acc[mt][1] = bias[mt][1];
                acc[mt][2] = bias[mt][2]; acc[mt][3] = bias[mt][3];
            }
            #pragma unroll
            for (int kt = 0; kt < 4; ++kt)
                #pragma unroll
                for (int mt = 0; mt < 2; ++mt)
                    acc[mt] = __builtin_amdgcn_mfma_f32_16x16x32_bf16(
                        win[mt][kt], bx[kt], acc[mt], 0, 0, 0);

            const uint tb = ((uint)(t0 + tt) * NBLK + (uint)b) * 16u;
            #pragma unroll
            for (int mt = 0; mt < 2; ++mt) {
                uint2 w;
                w.x = pk_bf16(acc[mt][0], acc[mt][1]);
                w.y = pk_bf16(acc[mt][2], acc[mt][3]);
                xin[(size_t)((tb + wid * 2 + mt) * 64u + lane)] = w;
            }
        }

        __syncthreads();                       // all stores issued
        if (tid == 0) {
            __threadfence();                   // agent fence: writeback to MALL
            __hip_atomic_store(&flags[b * NCHUNK + c], 1u,
                               __ATOMIC_RELEASE, __HIP_MEMORY_SCOPE_AGENT);
        }
        return;
    }

    // ------------------------- consumer: scan + parallel gates ------------------
    const int  bblk  = blockIdx.x * BTILE;
    const uint fbase = (uint)blockIdx.x * NCHUNK;
    const unsigned long long* __restrict__ xin64 = (const unsigned long long*)xin;

    short8 wrec[2][8];
    #pragma unroll
    for (int mt = 0; mt < 2; ++mt) {
        const int row = (wid * 2 + mt) * 16 + n15;
        #pragma unroll
        for (int kt = 0; kt < 8; ++kt)
            wrec[mt][kt] = load_wfrag_s(W_rec, NH, row, kt * 32 + q * 8, LOG2E);
    }

    for (int i = tid; i < 16 * 64; i += 512) {
        uint2 z; z.x = 0u; z.y = 0u;
        hlds[0][i] = z;
    }

    const uint loff = (uint)blockIdx.x * 1024u + (uint)(wid * 2) * 64u + (uint)lane;

    int nf = 0;   // next unconfirmed flag (wave 0; uniform across its lanes)
    // wave-parallel fence-free gate: lanes of wave 0 each load one flag of
    // [nf..target] (relaxed agent = sc1 MALL read), __all -> uniform advance.
    auto gate_to = [&](int target) {
        if (target > NCHUNK - 1) target = NCHUNK - 1;
        if (wid == 0) {
            while (nf <= target) {
                const int idx = nf + lane;
                bool ok = (idx > target) ||
                          (__hip_atomic_load(&flags[fbase + (uint)idx],
                                             __ATOMIC_RELAXED,
                                             __HIP_MEMORY_SCOPE_AGENT) != 0u);
                if (__all(ok)) nf = target + 1;
                else __builtin_amdgcn_s_sleep(4);
            }
        }
        __syncthreads();
    };

    gate_to(GATE / TCHUNK + 2);   // chunks 0..18: covers window-0 incl. prefetch

    unsigned long long xa[2], xb[2];
    #pragma unroll
    for (int mt = 0; mt < 2; ++mt)
        xa[mt] = __hip_atomic_load(&xin64[loff + mt * 64u],
                                   __ATOMIC_RELAXED, __HIP_MEMORY_SCOPE_AGENT);
    #pragma unroll
    for (int mt = 0; mt < 2; ++mt)
        xb[mt] = __hip_atomic_load(&xin64[8192u + loff + mt * 64u],
                                   __ATOMIC_RELAXED, __HIP_MEMORY_SCOPE_AGENT);

    __syncthreads();

    const int rbase = n15 * 4 + 2 * (q & 1);
    const int shalf = q >> 1;
    const int woff  = n15 * 4 + q;                               // fallback path
    // b128 write: byte offset in hlds[nxt] — slot 2wid+(q&1), woff base 4n15+(q&2)
    const int wbyte = (2 * wid + (q & 1)) * 512 + (4 * n15 + (q & 2)) * 8;

    auto step = [&](int t, unsigned long long (&X)[2]) {
        const int cur = t & 1, nxt = cur ^ 1;

        short8 bh[8];
        #pragma unroll
        for (int kt = 0; kt < 8; ++kt)
            bh[kt] = *(const short8*)&hlds[cur][(2 * kt + shalf) * 64 + rbase];

        f32x4 acc[2];
        #pragma unroll
        for (int mt = 0; mt < 2; ++mt) {
            const uint lo = (uint)X[mt], hi = (uint)(X[mt] >> 32);
            acc[mt][0] = bflo2f(lo);
            acc[mt][1] = bfhi2f(lo);
            acc[mt][2] = bflo2f(hi);
            acc[mt][3] = bfhi2f(hi);
        }

        {   // prefetch xin_{t+2} (sc1, floats across the lgkm-only barrier)
            const uint tp = (uint)((t + 2 < SEQ) ? (t + 2) : (SEQ - 1));
            const uint tb = tp * 8192u + loff;
            #pragma unroll
            for (int mt = 0; mt < 2; ++mt)
                X[mt] = __hip_atomic_load(&xin64[tb + mt * 64u],
                                          __ATOMIC_RELAXED,
                                          __HIP_MEMORY_SCOPE_AGENT);
        }

        __builtin_amdgcn_s_setprio(1);
        #pragma unroll
        for (int kt = 0; kt < 8; ++kt)
            #pragma unroll
            for (int mt = 0; mt < 2; ++mt)
                acc[mt] = __builtin_amdgcn_mfma_f32_16x16x32_bf16(
                    wrec[mt][kt], bh[kt], acc[mt], 0, 0, 0);
        __builtin_amdgcn_s_setprio(0);

        // sigmoid(a) = rcp(1 + 2^(-z)), z = log2e*a already in acc
        uint2 W[2];
        #pragma unroll
        for (int mt = 0; mt < 2; ++mt) {
            float h0 = __builtin_amdgcn_rcpf(1.0f + __builtin_amdgcn_exp2f(-acc[mt][0]));
            float h1 = __builtin_amdgcn_rcpf(1.0f + __builtin_amdgcn_exp2f(-acc[mt][1]));
            float h2 = __builtin_amdgcn_rcpf(1.0f + __builtin_amdgcn_exp2f(-acc[mt][2]));
            float h3 = __builtin_amdgcn_rcpf(1.0f + __builtin_amdgcn_exp2f(-acc[mt][3]));
            W[mt].x = pk_bf16(h0, h1);
            W[mt].y = pk_bf16(h2, h3);
        }
#if USE_PL16
        // lane-pair (l, l+16) exchange: even-q lanes collect mt0 of (q,q+1),
        // odd-q lanes collect mt1 of (q-1,q) -> one contiguous b128 per lane;
        // wave covers bytes [wid*1024, wid*1024+1024) bijectively (conflict-free).
        {
            upair sx = __builtin_amdgcn_permlane16_swap(W[0].x, W[1].x, false, false);
            upair sy = __builtin_amdgcn_permlane16_swap(W[0].y, W[1].y, false, false);
            uint4 w4;
            w4.x = sx[0]; w4.y = sy[0]; w4.z = sx[1]; w4.w = sy[1];
            *(uint4*)((char*)hlds[nxt] + wbyte) = w4;
        }
#else
        #pragma unroll
        for (int mt = 0; mt < 2; ++mt)
            hlds[nxt][(wid * 2 + mt) * 64 + woff] = W[mt];
#endif

        asm volatile("s_waitcnt lgkmcnt(0)" ::: "memory");
        __builtin_amdgcn_s_barrier();
    };

    #pragma unroll 1
    for (int t = 0; t < SEQ; t += 2) {
        if (t && (t & (GATE - 1)) == 0)
            gate_to((t >> 3) + GATE / TCHUNK + 2);   // covers window + prefetch
        step(t, xa);
        step(t + 1, xb);
    }

    // ---- output projection from hlds[0] (SEQ even): wave wid owns m-tile wid ----
    short8 wout[8];
    float  bo[4];
    {
        const int row = wid * 16 + n15;
        #pragma unroll
        for (int kt = 0; kt < 8; ++kt)
            wout[kt] = load_wfrag_s(W_out, NH, row, kt * 32 + q * 8, 1.0f);
        #pragma unroll
        for (int r = 0; r < 4; ++r)
            bo[r] = b_out[wid * 16 + q * 4 + r];
    }
    f32x4 oacc;
    oacc[0] = bo[0]; oacc[1] = bo[1]; oacc[2] = bo[2]; oacc[3] = bo[3];
    #pragma unroll
    for (int kt = 0; kt < 8; ++kt) {
        short8 bh = *(const short8*)&hlds[0][(2 * kt + shalf) * 64 + rbase];
        oacc = __builtin_amdgcn_mfma_f32_16x16x32_bf16(wout[kt], bh, oacc, 0, 0, 0);
    }
    #pragma unroll
    for (int r = 0; r < 4; ++r) {
        const int o = wid * 16 + q * 4 + r;
        out[(size_t)(bblk + n15) * NOUT + o] = oacc[r];
    }
}

// =================== fallback: exact r9 two-kernel path ===================
__global__ __launch_bounds__(256, 2)
void xin_gemm(const float* __restrict__ x,
              const float* __restrict__ W_in,
              const float* __restrict__ b_in,
              uint2* __restrict__ xin) {
    const int tid  = threadIdx.x;
    const int lane = tid & 63;
    const int wid  = tid >> 6;
    const int n15  = lane & 15;
    const int q    = lane >> 4;
    const int bblk = blockIdx.x * BTILE;
    const int t0   = blockIdx.y * TCHUNK;

    short8 win[4][4];
    float  bias[4][4];
    #pragma unroll
    for (int mt = 0; mt < 4; ++mt) {
        const int row = (wid * 4 + mt) * 16 + n15;
        #pragma unroll
        for (int kt = 0; kt < 4; ++kt)
            win[mt][kt] = load_wfrag_s(W_in, NIN, row, kt * 32 + q * 8, LOG2E);
        #pragma unroll
        for (int r = 0; r < 4; ++r)
            bias[mt][r] = LOG2E * b_in[(wid * 4 + mt) * 16 + q * 4 + r];
    }

    const float* xrow = x + ((size_t)(bblk + n15) * SEQ + t0) * NIN + q * 8;

    #pragma unroll 1
    for (int tt = 0; tt < TCHUNK; ++tt) {
        const float* xp = xrow + (size_t)tt * NIN;
        short8 bx[4];
        #pragma unroll
        for (int kt = 0; kt < 4; ++kt) {
            const float4* p = (const float4*)(xp + kt * 32);
            float4 a = p[0], b = p[1];
            union { short8 v; uint u[4]; } r;
            r.u[0] = pk_bf16(a.x, a.y);
            r.u[1] = pk_bf16(a.z, a.w);
            r.u[2] = pk_bf16(b.x, b.y);
            r.u[3] = pk_bf16(b.z, b.w);
            bx[kt] = r.v;
        }
        f32x4 acc[4];
        #pragma unroll
        for (int mt = 0; mt < 4; ++mt) {
            acc[mt][0] = bias[mt][0]; acc[mt][1] = bias[mt][1];
            acc[mt][2] = bias[mt][2]; acc[mt][3] = bias[mt][3];
        }
        #pragma unroll
        for (int kt = 0; kt < 4; ++kt)
            #pragma unroll
            for (int mt = 0; mt < 4; ++mt)
                acc[mt] = __builtin_amdgcn_mfma_f32_16x16x32_bf16(
                    win[mt][kt], bx[kt], acc[mt], 0, 0, 0);

        const uint tb = ((uint)(t0 + tt) * NBLK + blockIdx.x) * 16u;
        #pragma unroll
        for (int mt = 0; mt < 4; ++mt) {
            uint2 w;
            w.x = pk_bf16(acc[mt][0], acc[mt][1]);
            w.y = pk_bf16(acc[mt][2], acc[mt][3]);
            xin[(size_t)((tb + wid * 4 + mt) * 64u + lane)] = w;
        }
    }
}

__global__ __launch_bounds__(512, 2)
void elman_scan(const uint2* __restrict__ xin,
                const float* __restrict__ W_rec,
                const float* __restrict__ W_out,
                const float* __restrict__ b_out,
                float* __restrict__ out) {
    const int tid  = threadIdx.x;
    const int lane = tid & 63;
    const int wid  = tid >> 6;
    const int n15  = lane & 15;
    const int q    = lane >> 4;
    const int bblk = blockIdx.x * BTILE;

    __shared__ __align__(16) uint2 hlds[2][16 * 64];

    short8 wrec[2][8];
    #pragma unroll
    for (int mt = 0; mt < 2; ++mt) {
        const int row = (wid * 2 + mt) * 16 + n15;
        #pragma unroll
        for (int kt = 0; kt < 8; ++kt)
            wrec[mt][kt] = load_wfrag_s(W_rec, NH, row, kt * 32 + q * 8, LOG2E);
    }

    for (int i = tid; i < 16 * 64; i += 512) {
        uint2 z; z.x = 0u; z.y = 0u;
        hlds[0][i] = z;
    }

    const uint loff = (uint)blockIdx.x * 1024u + (uint)(wid * 2) * 64u + (uint)lane;

    uint2 xa[2], xb[2];
    #pragma unroll
    for (int mt = 0; mt < 2; ++mt) xa[mt] = xin[(size_t)(loff + mt * 64u)];
    #pragma unroll
    for (int mt = 0; mt < 2; ++mt) xb[mt] = xin[(size_t)(8192u + loff + mt * 64u)];

    __syncthreads();

    const int rbase = n15 * 4 + 2 * (q & 1);
    const int shalf = q >> 1;
    const int woff  = n15 * 4 + q;

    auto step = [&](int t, uint2 (&X)[2]) {
        const int cur = t & 1, nxt = cur ^ 1;
        short8 bh[8];
        #pragma unroll
        for (int kt = 0; kt < 8; ++kt)
            bh[kt] = *(const short8*)&hlds[cur][(2 * kt + shalf) * 64 + rbase];
        f32x4 acc[2];
        #pragma unroll
        for (int mt = 0; mt < 2; ++mt) {
            acc[mt][0] = bflo2f(X[mt].x);
            acc[mt][1] = bfhi2f(X[mt].x);
            acc[mt][2] = bflo2f(X[mt].y);
            acc[mt][3] = bfhi2f(X[mt].y);
        }
        {
            const uint tp = (uint)((t + 2 < SEQ) ? (t + 2) : (SEQ - 1));
            const uint tb = tp * 8192u + loff;
            #pragma unroll
            for (int mt = 0; mt < 2; ++mt) X[mt] = xin[(size_t)(tb + mt * 64u)];
        }
        __builtin_amdgcn_s_setprio(1);
        #pragma unroll
        for (int kt = 0; kt < 8; ++kt)
            #pragma unroll
            for (int mt = 0; mt < 2; ++mt)
                acc[mt] = __builtin_amdgcn_mfma_f32_16x16x32_bf16(
                    wrec[mt][kt], bh[kt], acc[mt], 0, 0, 0);
        __builtin_amdgcn_s_setprio(0);
        #pragma unroll
        for (int mt = 0; mt < 2; ++mt) {
            float h0 = __builtin_amdgcn_rcpf(1.0f + __builtin_amdgcn_exp2f(-acc[mt][0]));
            float h1 = __builtin_amdgcn_rcpf(1.0f + __builtin_amdgcn_exp2f(-acc[mt][1]));
            float h2 = __builtin_amdgcn_rcpf(1.0f + __builtin_amdgcn_exp2f(-acc[mt][2]));
            float h3 = __builtin_amdgcn_rcpf(1.0f + __builtin_amdgcn_exp2f(-acc[mt][3]));
            uint2 w;
            w.x = pk_bf16(h0, h1);
            w.y = pk_bf16(h2, h3);
            hlds[nxt][(wid * 2 + mt) * 64 + woff] = w;
        }
        asm volatile("s_waitcnt lgkmcnt(0)" ::: "memory");
        __builtin_amdgcn_s_barrier();
    };

    #pragma unroll 1
    for (int t = 0; t < SEQ; t += 2) {
        step(t, xa);
        step(t + 1, xb);
    }

    short8 wout[8];
    float  bo[4];
    {
        const int row = wid * 16 + n15;
        #pragma unroll
        for (int kt = 0; kt < 8; ++kt)
            wout[kt] = load_wfrag_s(W_out, NH, row, kt * 32 + q * 8, 1.0f);
        #pragma unroll
        for (int r = 0; r < 4; ++r)
            bo[r] = b_out[wid * 16 + q * 4 + r];
    }
    f32x4 oacc;
    oacc[0] = bo[0]; oacc[1] = bo[1]; oacc[2] = bo[2]; oacc[3] = bo[3];
    #pragma unroll
    for (int kt = 0; kt < 8; ++kt) {
        short8 bh = *(const short8*)&hlds[0][(2 * kt + shalf) * 64 + rbase];
        oacc = __builtin_amdgcn_mfma_f32_16x16x32_bf16(wout[kt], bh, oacc, 0, 0, 0);
    }
    #pragma unroll
    for (int r = 0; r < 4; ++r) {
        const int o = wid * 16 + q * 4 + r;
        out[(size_t)(bblk + n15) * NOUT + o] = oacc[r];
    }
}

extern "C" void kernel_launch(void* const* d_in, const int* in_sizes, int n_in,
                              void* d_out, int out_size, void* d_ws, size_t ws_size,
                              hipStream_t stream) {
    const float* x     = (const float*)d_in[0];
    const float* W_in  = (const float*)d_in[1];
    const float* b_in  = (const float*)d_in[2];
    const float* W_rec = (const float*)d_in[3];
    const float* W_out = (const float*)d_in[4];
    const float* b_out = (const float*)d_in[5];
    float* out = (float*)d_out;

    const size_t xin_bytes  = (size_t)SEQ * BATCH * NH * sizeof(ushort);  // 134 MB
    const size_t flag_bytes = (size_t)NBLK * NCHUNK * sizeof(uint);       // 8 KB

    if (ws_size >= xin_bytes + flag_bytes) {
        uint2* xin  = (uint2*)d_ws;
        uint* flags = (uint*)((char*)d_ws + xin_bytes);
        hipMemsetAsync(flags, 0, flag_bytes, stream);
        // 8 consumers (dispatched first) + 2048 producers; 96 KB dynamic LDS
        // forces 1 block/CU so producers never co-reside with scan CUs.
        elman_fused<<<NBLK + NBLK * NCHUNK, 512, 96 * 1024, stream>>>(
            x, W_in, b_in, W_rec, W_out, b_out, out, xin, flags);
    } else if (ws_size >= xin_bytes) {
        uint2* xin = (uint2*)d_ws;
        dim3 g1(NBLK, SEQ / TCHUNK);
        xin_gemm<<<g1, 256, 0, stream>>>(x, W_in, b_in, xin);
        elman_scan<<<NBLK, 512, 0, stream>>>(xin, W_rec, W_out, b_out, out);
    }
}